// Round 1
// baseline (429.557 us; speedup 1.0000x reference)
//
#include <hip/hip_runtime.h>

typedef __bf16 bf16_t;
typedef bf16_t bf16x8 __attribute__((ext_vector_type(8)));
typedef float f32x4 __attribute__((ext_vector_type(4)));

#define MFMA16(a, b, c) __builtin_amdgcn_mfma_f32_16x16x32_bf16(a, b, c, 0, 0, 0)

__device__ inline void async_copy16(const bf16_t* g, bf16_t* l) {
  __builtin_amdgcn_global_load_lds(
      (const __attribute__((address_space(1))) void*)g,
      (__attribute__((address_space(3))) void*)l, 16, 0, 0);
}

// LDS tiles are stored as 64-col rows of 8 chunks (16B each); chunk c8 of row r
// lives at slot (c8 ^ (r & 7)) -> ds_read_b128 fragment reads spread evenly
// over all 32 banks (8-cycle floor) instead of 2x conflicts.
__device__ inline bf16x8 lds_frag(const bf16_t* lds, int row, int c8) {
  return *(const bf16x8*)(lds + row * 64 + ((c8 ^ (row & 7)) << 3));
}

// Stage a rows x 64-col bf16 tile (NCHUNK = rows*8 chunks) global -> LDS.
// LDS dest is contiguous in lane order (global_load_lds constraint); the XOR
// swizzle is applied by permuting WHICH global chunk each lane fetches.
template <int NCHUNK>
__device__ inline void stage_tile(const bf16_t* __restrict__ g, size_t ld,
                                  bf16_t* lds, int tid) {
#pragma unroll
  for (int it = 0; it < NCHUNK / 256; ++it) {
    int f = it * 256 + tid;
    int row = f >> 3;
    int c8 = (f & 7) ^ (row & 7);
    async_copy16(g + (size_t)row * ld + c8 * 8, lds + f * 8);
  }
}

// -------------------- fp32 -> bf16 conversion (all 6 tensors fused) ---------
__global__ __launch_bounds__(256) void convert_kernel(
    const float* __restrict__ q, const float* __restrict__ mem,
    const float* __restrict__ wq, const float* __restrict__ wk,
    const float* __restrict__ wv, const float* __restrict__ wo,
    bf16_t* Xq, bf16_t* Xm, bf16_t* Wqb, bf16_t* Wkb, bf16_t* Wvb,
    bf16_t* Wob) {
  size_t i = ((size_t)blockIdx.x * 256 + threadIdx.x) * 8;
  const float* src;
  bf16_t* dst;
  size_t off;
  if (i < 8388608u)        { src = q;   dst = Xq;  off = i; }
  else if (i < 16777216u)  { src = mem; dst = Xm;  off = i - 8388608u; }
  else if (i < 17825792u)  { src = wq;  dst = Wqb; off = i - 16777216u; }
  else if (i < 18874368u)  { src = wk;  dst = Wkb; off = i - 17825792u; }
  else if (i < 19922944u)  { src = wv;  dst = Wvb; off = i - 18874368u; }
  else                     { src = wo;  dst = Wob; off = i - 19922944u; }
  float4 f0 = *(const float4*)(src + off);
  float4 f1 = *(const float4*)(src + off + 4);
  union { bf16_t h[8]; uint4 u; } t;
  t.h[0] = (bf16_t)f0.x; t.h[1] = (bf16_t)f0.y;
  t.h[2] = (bf16_t)f0.z; t.h[3] = (bf16_t)f0.w;
  t.h[4] = (bf16_t)f1.x; t.h[5] = (bf16_t)f1.y;
  t.h[6] = (bf16_t)f1.z; t.h[7] = (bf16_t)f1.w;
  *(uint4*)(dst + off) = t.u;
}

// -------------------- NT GEMM: C[8192,1024] = A[8192,1024] * B[1024,1024]^T -
// m97 structure: 128x128 tile, BK=64, 4 waves (2x2 of 64x64), width-16
// global_load_lds staging, 16x16x32 bf16 MFMA.
template <bool WF32>
__global__ __launch_bounds__(256) void gemm_nt(
    const bf16_t* __restrict__ A, const bf16_t* __restrict__ Bw,
    const float* __restrict__ bias, void* __restrict__ Cout) {
  __shared__ bf16_t As[128 * 64];
  __shared__ bf16_t Bs[128 * 64];
  const int tid = threadIdx.x;
  const int wave = tid >> 6, lane = tid & 63, quad = lane >> 4, c = lane & 15;
  const int wm = (wave & 1) * 64, wn = (wave >> 1) * 64;
  const size_t bm = blockIdx.x, bn = blockIdx.y;
  const bf16_t* Ab = A + bm * 128 * 1024;
  const bf16_t* Bb = Bw + bn * 128 * 1024;
  const f32x4 z4 = {0.f, 0.f, 0.f, 0.f};
  f32x4 acc[4][4];
#pragma unroll
  for (int i = 0; i < 4; ++i)
#pragma unroll
    for (int j = 0; j < 4; ++j) acc[i][j] = z4;

  for (int kt = 0; kt < 16; ++kt) {
    if (kt) __syncthreads();
    stage_tile<1024>(Ab + kt * 64, 1024, As, tid);
    stage_tile<1024>(Bb + kt * 64, 1024, Bs, tid);
    __syncthreads();
#pragma unroll
    for (int ks = 0; ks < 2; ++ks) {
      bf16x8 af[4], bfr[4];
#pragma unroll
      for (int i = 0; i < 4; ++i)
        af[i] = lds_frag(As, wm + 16 * i + c, ks * 4 + quad);
#pragma unroll
      for (int j = 0; j < 4; ++j)
        bfr[j] = lds_frag(Bs, wn + 16 * j + c, ks * 4 + quad);
#pragma unroll
      for (int i = 0; i < 4; ++i)
#pragma unroll
        for (int j = 0; j < 4; ++j)
          acc[i][j] = MFMA16(af[i], bfr[j], acc[i][j]);
    }
  }
#pragma unroll
  for (int i = 0; i < 4; ++i)
#pragma unroll
    for (int j = 0; j < 4; ++j) {
      int gr0 = (int)bm * 128 + wm + 16 * i + quad * 4;
      int gc = (int)bn * 128 + wn + 16 * j + c;
      float bvv = bias[gc];
#pragma unroll
      for (int r = 0; r < 4; ++r) {
        float v = acc[i][j][r] + bvv;
        size_t idx = (size_t)(gr0 + r) * 1024 + gc;
        if (WF32)
          ((float*)Cout)[idx] = v;
        else
          ((bf16_t*)Cout)[idx] = (bf16_t)v;
      }
    }
}

// -------------------- V transpose: Vp[b][k][d] -> Vt[b][d][k] ---------------
__global__ __launch_bounds__(256) void transpose_kernel(
    const bf16_t* __restrict__ Vp, bf16_t* __restrict__ Vt) {
  __shared__ bf16_t T[64][72];  // +8 pad breaks bank alignment on the gather
  const int tid = threadIdx.x;
  const int kt = blockIdx.x, dt = blockIdx.y, b = blockIdx.z;
#pragma unroll
  for (int it = 0; it < 2; ++it) {
    int f = it * 2048 + tid * 8;
    int row = f >> 6, col = f & 63;
    const bf16_t* src =
        Vp + ((size_t)b * 1024 + kt * 64 + row) * 1024 + dt * 64 + col;
    *(uint4*)&T[row][col] = *(const uint4*)src;
  }
  __syncthreads();
#pragma unroll
  for (int it = 0; it < 2; ++it) {
    int f = it * 2048 + tid * 8;
    int drow = f >> 6, kcol = f & 63;
    union { bf16_t h[8]; uint4 u; } t;
#pragma unroll
    for (int jj = 0; jj < 8; ++jj) t.h[jj] = T[kcol + jj][drow];
    bf16_t* dst =
        Vt + ((size_t)b * 1024 + dt * 64 + drow) * 1024 + kt * 64 + kcol;
    *(uint4*)dst = t.u;
  }
}

// -------------------- fused attention -------------------------------------
// One workgroup per (b, h, 64 q-rows). Pass 1: online row stats (m, l) from
// QK^T only. Pass 2: recompute S (bit-identical), P = exp(s-m)/l, accumulate
// O = P V via LDS round-trip of P, and column-sum P into covsum for coverage.
__global__ __launch_bounds__(256) void attn_kernel(
    const bf16_t* __restrict__ Qp, const bf16_t* __restrict__ Kp,
    const bf16_t* __restrict__ Vt, const float* __restrict__ coverage,
    const float* __restrict__ Wcov, bf16_t* __restrict__ Hb,
    float* __restrict__ part) {
  __shared__ bf16_t Qs[64 * 64];
  __shared__ bf16_t Ks[64 * 64];
  __shared__ bf16_t Vs[64 * 64];
  __shared__ bf16_t Ps[4][16 * 64];
  __shared__ float covb[64];
  __shared__ float covsum[1024];
  const int tid = threadIdx.x;
  const int wave = tid >> 6, lane = tid & 63, quad = lane >> 4, c = lane & 15;
  const int q0t = blockIdx.x, h = blockIdx.y, b = blockIdx.z;
  const int q0 = q0t * 64;
  const float wc = Wcov[h];
  for (int i = tid; i < 1024; i += 256) covsum[i] = 0.f;

  stage_tile<512>(Qp + ((size_t)(b * 1024 + q0)) * 1024 + h * 64, 1024, Qs,
                  tid);

  float m[4], l[4];
#pragma unroll
  for (int r = 0; r < 4; ++r) {
    m[r] = -1e30f;
    l[r] = 0.f;
  }
  const f32x4 z4 = {0.f, 0.f, 0.f, 0.f};

  // ---- pass 1: row stats ----
  for (int kt = 0; kt < 16; ++kt) {
    const int k0 = kt * 64;
    if (kt) __syncthreads();
    if (tid < 64) covb[tid] = coverage[b * 1024 + k0 + tid] * wc;
    stage_tile<512>(Kp + ((size_t)(b * 1024 + k0)) * 1024 + h * 64, 1024, Ks,
                    tid);
    __syncthreads();
    f32x4 S[4] = {z4, z4, z4, z4};
#pragma unroll
    for (int ks = 0; ks < 2; ++ks) {
      bf16x8 a = lds_frag(Qs, wave * 16 + c, ks * 4 + quad);
#pragma unroll
      for (int j = 0; j < 4; ++j)
        S[j] = MFMA16(a, lds_frag(Ks, j * 16 + c, ks * 4 + quad), S[j]);
    }
    float sv[4][4];
#pragma unroll
    for (int j = 0; j < 4; ++j) {
      float cb = covb[j * 16 + c];
#pragma unroll
      for (int r = 0; r < 4; ++r) sv[j][r] = S[j][r] * 0.125f + cb;
    }
#pragma unroll
    for (int r = 0; r < 4; ++r) {
      float mx = fmaxf(fmaxf(sv[0][r], sv[1][r]), fmaxf(sv[2][r], sv[3][r]));
      mx = fmaxf(mx, __shfl_xor(mx, 1));
      mx = fmaxf(mx, __shfl_xor(mx, 2));
      mx = fmaxf(mx, __shfl_xor(mx, 4));
      mx = fmaxf(mx, __shfl_xor(mx, 8));
      float nm = fmaxf(m[r], mx);
      float s = __expf(sv[0][r] - nm) + __expf(sv[1][r] - nm) +
                __expf(sv[2][r] - nm) + __expf(sv[3][r] - nm);
      s += __shfl_xor(s, 1);
      s += __shfl_xor(s, 2);
      s += __shfl_xor(s, 4);
      s += __shfl_xor(s, 8);
      l[r] = l[r] * __expf(m[r] - nm) + s;
      m[r] = nm;
    }
  }
  float linv[4];
#pragma unroll
  for (int r = 0; r < 4; ++r) linv[r] = 1.f / l[r];

  f32x4 O[4] = {z4, z4, z4, z4};
  bf16_t* Pw = &Ps[wave][0];

  // ---- pass 2: P, O = P V, column sums ----
  for (int kt = 0; kt < 16; ++kt) {
    const int k0 = kt * 64;
    __syncthreads();
    if (tid < 64) covb[tid] = coverage[b * 1024 + k0 + tid] * wc;
    stage_tile<512>(Kp + ((size_t)(b * 1024 + k0)) * 1024 + h * 64, 1024, Ks,
                    tid);
    stage_tile<512>(Vt + ((size_t)(b * 1024 + h * 64)) * 1024 + k0, 1024, Vs,
                    tid);
    __syncthreads();
    f32x4 S[4] = {z4, z4, z4, z4};
#pragma unroll
    for (int ks = 0; ks < 2; ++ks) {
      bf16x8 a = lds_frag(Qs, wave * 16 + c, ks * 4 + quad);
#pragma unroll
      for (int j = 0; j < 4; ++j)
        S[j] = MFMA16(a, lds_frag(Ks, j * 16 + c, ks * 4 + quad), S[j]);
    }
#pragma unroll
    for (int j = 0; j < 4; ++j) {
      float cb = covb[j * 16 + c];
      float csj = 0.f;
#pragma unroll
      for (int r = 0; r < 4; ++r) {
        float svv = S[j][r] * 0.125f + cb;
        float p = __expf(svv - m[r]) * linv[r];
        csj += p;
        int row = quad * 4 + r;
        int col = j * 16 + c;
        Pw[row * 64 + (((col >> 3) ^ (row & 7)) << 3) + (col & 7)] = (bf16_t)p;
      }
      csj += __shfl_xor(csj, 16);
      csj += __shfl_xor(csj, 32);
      if (quad == 0) atomicAdd(&covsum[k0 + j * 16 + c], csj);
    }
#pragma unroll
    for (int ks = 0; ks < 2; ++ks) {
      bf16x8 a = lds_frag(Pw, c, ks * 4 + quad);  // same-wave RAW: in-order LDS
#pragma unroll
      for (int j = 0; j < 4; ++j)
        O[j] = MFMA16(a, lds_frag(Vs, j * 16 + c, ks * 4 + quad), O[j]);
    }
  }
#pragma unroll
  for (int j = 0; j < 4; ++j)
#pragma unroll
    for (int r = 0; r < 4; ++r) {
      size_t row = (size_t)b * 1024 + q0 + wave * 16 + quad * 4 + r;
      Hb[row * 1024 + h * 64 + j * 16 + c] = (bf16_t)O[j][r];
    }
  __syncthreads();
  float* ps = part + ((size_t)b * 256 + h * 16 + q0t) * 1024;
  for (int i = tid; i < 1024; i += 256) ps[i] = covsum[i];
}

// -------------------- coverage reduce --------------------------------------
__global__ __launch_bounds__(256) void cov_reduce(
    const float* __restrict__ part, const float* __restrict__ coverage,
    float* __restrict__ outcov) {
  int i = blockIdx.x * 256 + threadIdx.x;  // 8192 = B*TK
  int b = i >> 10, k = i & 1023;
  const float* p = part + (size_t)b * 256 * 1024 + k;
  float s = 0.f;
  for (int j = 0; j < 256; ++j) s += p[(size_t)j * 1024];
  outcov[i] = coverage[i] + s * 0.0625f;  // mean over 16 heads
}

extern "C" void kernel_launch(void* const* d_in, const int* in_sizes, int n_in,
                              void* d_out, int out_size, void* d_ws,
                              size_t ws_size, hipStream_t stream) {
  const float* query = (const float*)d_in[0];
  const float* memory = (const float*)d_in[1];
  const float* coverage = (const float*)d_in[2];
  const float* Wq = (const float*)d_in[3];
  const float* bq = (const float*)d_in[4];
  const float* Wk = (const float*)d_in[5];
  const float* bk = (const float*)d_in[6];
  const float* Wv = (const float*)d_in[7];
  const float* bv = (const float*)d_in[8];
  const float* Wo = (const float*)d_in[9];
  const float* bo = (const float*)d_in[10];
  const float* Wcov = (const float*)d_in[11];

  char* w = (char*)d_ws;
  const size_t MB = 1024 * 1024;
  bf16_t* Xq = (bf16_t*)(w + 0);
  bf16_t* Xm = (bf16_t*)(w + 16 * MB);
  bf16_t* Wqb = (bf16_t*)(w + 32 * MB);
  bf16_t* Wkb = (bf16_t*)(w + 34 * MB);
  bf16_t* Wvb = (bf16_t*)(w + 36 * MB);
  bf16_t* Wob = (bf16_t*)(w + 38 * MB);
  bf16_t* Qp = (bf16_t*)(w + 40 * MB);
  bf16_t* Kp = (bf16_t*)(w + 56 * MB);
  bf16_t* Vp = (bf16_t*)(w + 72 * MB);
  bf16_t* Vt = (bf16_t*)(w + 88 * MB);
  bf16_t* Hb = (bf16_t*)(w + 0);       // reuses Xq (dead after projections)
  float* part = (float*)(w + 16 * MB); // reuses Xm (dead after projections)

  float* out = (float*)d_out;
  float* outcov = out + (size_t)8 * 1024 * 1024;

  convert_kernel<<<10240, 256, 0, stream>>>(query, memory, Wq, Wk, Wv, Wo, Xq,
                                            Xm, Wqb, Wkb, Wvb, Wob);
  gemm_nt<false><<<dim3(64, 8), 256, 0, stream>>>(Xq, Wqb, bq, Qp);
  gemm_nt<false><<<dim3(64, 8), 256, 0, stream>>>(Xm, Wkb, bk, Kp);
  gemm_nt<false><<<dim3(64, 8), 256, 0, stream>>>(Xm, Wvb, bv, Vp);
  transpose_kernel<<<dim3(16, 16, 8), 256, 0, stream>>>(Vp, Vt);
  attn_kernel<<<dim3(16, 16, 8), 256, 0, stream>>>(Qp, Kp, Vt, coverage, Wcov,
                                                   Hb, part);
  gemm_nt<true><<<dim3(64, 8), 256, 0, stream>>>(Hb, Wob, bo, out);
  cov_reduce<<<32, 256, 0, stream>>>(part, coverage, outcov);
}

// Round 2
// 348.400 us; speedup vs baseline: 1.2329x; 1.2329x over previous
//
#include <hip/hip_runtime.h>

typedef __bf16 bf16_t;
typedef bf16_t bf16x8 __attribute__((ext_vector_type(8)));
typedef float f32x4 __attribute__((ext_vector_type(4)));

#define MFMA16(a, b, c) __builtin_amdgcn_mfma_f32_16x16x32_bf16(a, b, c, 0, 0, 0)

#define LOG2E 1.44269504f
#define C1 0.18033688f  // log2(e)/8 (SCALE = sqrt(64) = 8)

__device__ inline void async_copy16(const bf16_t* g, bf16_t* l) {
  __builtin_amdgcn_global_load_lds(
      (const __attribute__((address_space(1))) void*)g,
      (__attribute__((address_space(3))) void*)l, 16, 0, 0);
}

// LDS tiles: 64-col rows of 8 chunks (16B); chunk c8 of row r lives at slot
// (c8 ^ (r & 7)) -> ds_read_b128 frag reads spread over all 32 banks.
__device__ inline bf16x8 lds_frag(const bf16_t* lds, int row, int c8) {
  return *(const bf16x8*)(lds + row * 64 + ((c8 ^ (row & 7)) << 3));
}

template <int NCHUNK>
__device__ inline void stage_tile(const bf16_t* __restrict__ g, size_t ld,
                                  bf16_t* lds, int tid) {
#pragma unroll
  for (int it = 0; it < NCHUNK / 256; ++it) {
    int f = it * 256 + tid;
    int row = f >> 3;
    int c8 = (f & 7) ^ (row & 7);
    async_copy16(g + (size_t)row * ld + c8 * 8, lds + f * 8);
  }
}

// ------------- fp32 -> bf16 conversion (6 tensors) + coverage-out init ------
__global__ __launch_bounds__(256) void convert_kernel(
    const float* __restrict__ q, const float* __restrict__ mem,
    const float* __restrict__ wq, const float* __restrict__ wk,
    const float* __restrict__ wv, const float* __restrict__ wo,
    const float* __restrict__ coverage, bf16_t* Xq, bf16_t* Xm, bf16_t* Wqb,
    bf16_t* Wkb, bf16_t* Wvb, bf16_t* Wob, float* covout) {
  size_t i = ((size_t)blockIdx.x * 256 + threadIdx.x) * 8;
  if (i >= 20971520u) {  // coverage -> covout init (f32 copy)
    size_t off = i - 20971520u;
    *(float4*)(covout + off) = *(const float4*)(coverage + off);
    *(float4*)(covout + off + 4) = *(const float4*)(coverage + off + 4);
    return;
  }
  const float* src;
  bf16_t* dst;
  size_t off;
  if (i < 8388608u)        { src = q;   dst = Xq;  off = i; }
  else if (i < 16777216u)  { src = mem; dst = Xm;  off = i - 8388608u; }
  else if (i < 17825792u)  { src = wq;  dst = Wqb; off = i - 16777216u; }
  else if (i < 18874368u)  { src = wk;  dst = Wkb; off = i - 17825792u; }
  else if (i < 19922944u)  { src = wv;  dst = Wvb; off = i - 18874368u; }
  else                     { src = wo;  dst = Wob; off = i - 19922944u; }
  float4 f0 = *(const float4*)(src + off);
  float4 f1 = *(const float4*)(src + off + 4);
  union { bf16_t h[8]; uint4 u; } t;
  t.h[0] = (bf16_t)f0.x; t.h[1] = (bf16_t)f0.y;
  t.h[2] = (bf16_t)f0.z; t.h[3] = (bf16_t)f0.w;
  t.h[4] = (bf16_t)f1.x; t.h[5] = (bf16_t)f1.y;
  t.h[6] = (bf16_t)f1.z; t.h[7] = (bf16_t)f1.w;
  *(uint4*)(dst + off) = t.u;
}

// ------------- NT GEMM: C[8192,1024] = A[8192,1024] * B[1024,1024]^T --------
// MODE 0: write bf16 C row-major. MODE 1: write f32 C row-major.
// MODE 2: write bf16 C transposed per batch -> Vt[b][col][row%1024]
template <int MODE>
__global__ __launch_bounds__(256) void gemm_nt(
    const bf16_t* __restrict__ A, const bf16_t* __restrict__ Bw,
    const float* __restrict__ bias, void* __restrict__ Cout) {
  __shared__ bf16_t As[128 * 64];
  __shared__ bf16_t Bs[128 * 64];
  const int tid = threadIdx.x;
  const int wave = tid >> 6, lane = tid & 63, quad = lane >> 4, c = lane & 15;
  const int wm = (wave & 1) * 64, wn = (wave >> 1) * 64;
  const size_t bm = blockIdx.x, bn = blockIdx.y;
  const bf16_t* Ab = A + bm * 128 * 1024;
  const bf16_t* Bb = Bw + bn * 128 * 1024;
  const f32x4 z4 = {0.f, 0.f, 0.f, 0.f};
  f32x4 acc[4][4];
#pragma unroll
  for (int i = 0; i < 4; ++i)
#pragma unroll
    for (int j = 0; j < 4; ++j) acc[i][j] = z4;

  for (int kt = 0; kt < 16; ++kt) {
    if (kt) __syncthreads();
    stage_tile<1024>(Ab + kt * 64, 1024, As, tid);
    stage_tile<1024>(Bb + kt * 64, 1024, Bs, tid);
    __syncthreads();
#pragma unroll
    for (int ks = 0; ks < 2; ++ks) {
      bf16x8 af[4], bfr[4];
#pragma unroll
      for (int i = 0; i < 4; ++i)
        af[i] = lds_frag(As, wm + 16 * i + c, ks * 4 + quad);
#pragma unroll
      for (int j = 0; j < 4; ++j)
        bfr[j] = lds_frag(Bs, wn + 16 * j + c, ks * 4 + quad);
#pragma unroll
      for (int i = 0; i < 4; ++i)
#pragma unroll
        for (int j = 0; j < 4; ++j)
          acc[i][j] = MFMA16(af[i], bfr[j], acc[i][j]);
    }
  }
#pragma unroll
  for (int i = 0; i < 4; ++i)
#pragma unroll
    for (int j = 0; j < 4; ++j) {
      int gc = (int)bn * 128 + wn + 16 * j + c;
      float bvv = bias[gc];
      if (MODE == 2) {
        // rows of C are (b, k); write Vt[b][gc][k], 4 consecutive k packed
        int b = (int)(bm >> 3);
        int kk = (int)(bm & 7) * 128 + wm + 16 * i + quad * 4;
        union { bf16_t h4[4]; uint2 u; } pk;
#pragma unroll
        for (int r = 0; r < 4; ++r) pk.h4[r] = (bf16_t)(acc[i][j][r] + bvv);
        *(uint2*)((bf16_t*)Cout + ((size_t)(b * 1024 + gc)) * 1024 + kk) = pk.u;
      } else {
        int gr0 = (int)bm * 128 + wm + 16 * i + quad * 4;
#pragma unroll
        for (int r = 0; r < 4; ++r) {
          float v = acc[i][j][r] + bvv;
          size_t idx = (size_t)(gr0 + r) * 1024 + gc;
          if (MODE == 1)
            ((float*)Cout)[idx] = v;
          else
            ((bf16_t*)Cout)[idx] = (bf16_t)v;
        }
      }
    }
}

// ------------- fused attention, single pass, no-max softmax -----------------
// S^T = K·Q^T  (C: col=q=lane&15, row=key=quad*4+r)  ->  exp2 -> P~ (bf16,
// packed b64 into per-wave LDS q-rows) -> O^T = V^T·P~^T.  l accumulates
// per-lane, reduced across quads once after the k-loop; O normalized by 1/l
// in the epilogue (col of O^T is also q). 1/l stored for the coverage kernel.
__global__ __launch_bounds__(256) void attn_fwd(
    const bf16_t* __restrict__ Qp, const bf16_t* __restrict__ Kp,
    const bf16_t* __restrict__ Vt, const float* __restrict__ coverage,
    const float* __restrict__ Wcov, bf16_t* __restrict__ Hb,
    float* __restrict__ linvG) {
  __shared__ bf16_t Qs[64 * 64];
  __shared__ bf16_t Ks[64 * 64];
  __shared__ bf16_t Vs[64 * 64];
  __shared__ bf16_t Ps[4][16 * 64];
  __shared__ float covb[1024];
  const int tid = threadIdx.x;
  const int wave = tid >> 6, lane = tid & 63, quad = lane >> 4, c = lane & 15;
  const int q0 = blockIdx.x * 64, h = blockIdx.y, b = blockIdx.z;
  const float wcl = Wcov[h] * LOG2E;
  const f32x4 z4 = {0.f, 0.f, 0.f, 0.f};

  stage_tile<512>(Qp + ((size_t)(b * 1024 + q0)) * 1024 + h * 64, 1024, Qs,
                  tid);
  for (int i = tid; i < 1024; i += 256) covb[i] = coverage[b * 1024 + i] * wcl;

  float lpart = 0.f;
  f32x4 O[4] = {z4, z4, z4, z4};
  bf16x8 qf0, qf1;
  bf16_t* Pw = &Ps[wave][0];

  for (int kt = 0; kt < 16; ++kt) {
    const int k0 = kt * 64;
    if (kt) __syncthreads();
    stage_tile<512>(Kp + ((size_t)(b * 1024 + k0)) * 1024 + h * 64, 1024, Ks,
                    tid);
    stage_tile<512>(Vt + ((size_t)(b * 1024 + h * 64)) * 1024 + k0, 1024, Vs,
                    tid);
    __syncthreads();
    if (kt == 0) {
      qf0 = lds_frag(Qs, wave * 16 + c, quad);
      qf1 = lds_frag(Qs, wave * 16 + c, 4 + quad);
    }
    f32x4 S[4] = {z4, z4, z4, z4};
#pragma unroll
    for (int j = 0; j < 4; ++j) {
      S[j] = MFMA16(lds_frag(Ks, j * 16 + c, quad), qf0, S[j]);
      S[j] = MFMA16(lds_frag(Ks, j * 16 + c, 4 + quad), qf1, S[j]);
    }
#pragma unroll
    for (int j = 0; j < 4; ++j) {
      f32x4 cb = *(const f32x4*)&covb[k0 + j * 16 + quad * 4];
      union { bf16_t h4[4]; uint2 u; } pk;
#pragma unroll
      for (int r = 0; r < 4; ++r) {
        float p = exp2f(S[j][r] * C1 + cb[r]);
        lpart += p;
        pk.h4[r] = (bf16_t)p;
      }
      int k8 = j * 2 + (quad >> 1);
      *(uint2*)(Pw + c * 64 + ((k8 ^ (c & 7)) << 3) + (quad & 1) * 4) = pk.u;
    }
    // PV: same-wave LDS RAW (in-order pipe), no barrier needed
#pragma unroll
    for (int ks = 0; ks < 2; ++ks) {
      bf16x8 pb = *(const bf16x8*)(Pw + c * 64 + (((ks * 4 + quad) ^ (c & 7)) << 3));
#pragma unroll
      for (int j = 0; j < 4; ++j)
        O[j] = MFMA16(lds_frag(Vs, j * 16 + c, ks * 4 + quad), pb, O[j]);
    }
  }

  lpart += __shfl_xor(lpart, 16);
  lpart += __shfl_xor(lpart, 32);
  float linv = 1.f / lpart;
  if (quad == 0)
    linvG[((size_t)(b * 16 + h)) * 1024 + q0 + wave * 16 + c] = linv;

  size_t rowbase = ((size_t)(b * 1024 + q0 + wave * 16 + c)) * 1024 + h * 64;
#pragma unroll
  for (int j = 0; j < 4; ++j) {
    union { bf16_t h4[4]; uint2 u; } pk;
#pragma unroll
    for (int r = 0; r < 4; ++r) pk.h4[r] = (bf16_t)(O[j][r] * linv);
    *(uint2*)(Hb + rowbase + j * 16 + quad * 4) = pk.u;
  }
}

// ------------- coverage: recompute P column-sums with stored 1/l ------------
// Block = (64 keys, h, b); K-frags register-resident; loop all 16 q-tiles.
__global__ __launch_bounds__(256) void cov_kernel(
    const bf16_t* __restrict__ Qp, const bf16_t* __restrict__ Kp,
    const float* __restrict__ coverage, const float* __restrict__ Wcov,
    const float* __restrict__ linvG, float* __restrict__ covout) {
  __shared__ bf16_t Ks[64 * 64];
  __shared__ bf16_t Qs[64 * 64];
  __shared__ float covb[64];
  __shared__ float covsum[64];
  const int tid = threadIdx.x;
  const int wave = tid >> 6, lane = tid & 63, quad = lane >> 4, c = lane & 15;
  const int k0 = blockIdx.x * 64, h = blockIdx.y, b = blockIdx.z;
  const float wcl = Wcov[h] * LOG2E;
  const f32x4 z4 = {0.f, 0.f, 0.f, 0.f};

  stage_tile<512>(Kp + ((size_t)(b * 1024 + k0)) * 1024 + h * 64, 1024, Ks,
                  tid);
  if (tid < 64) {
    covb[tid] = coverage[b * 1024 + k0 + tid] * wcl;
    covsum[tid] = 0.f;
  }
  float cs[4][4] = {};
  bf16x8 kf0[4], kf1[4];

  for (int qt = 0; qt < 16; ++qt) {
    if (qt) __syncthreads();
    stage_tile<512>(Qp + ((size_t)(b * 1024 + qt * 64)) * 1024 + h * 64, 1024,
                    Qs, tid);
    float lv = linvG[((size_t)(b * 16 + h)) * 1024 + qt * 64 + wave * 16 + c];
    __syncthreads();
    if (qt == 0) {
#pragma unroll
      for (int j = 0; j < 4; ++j) {
        kf0[j] = lds_frag(Ks, j * 16 + c, quad);
        kf1[j] = lds_frag(Ks, j * 16 + c, 4 + quad);
      }
    }
    bf16x8 qf0 = lds_frag(Qs, wave * 16 + c, quad);
    bf16x8 qf1 = lds_frag(Qs, wave * 16 + c, 4 + quad);
    f32x4 S[4] = {z4, z4, z4, z4};
#pragma unroll
    for (int j = 0; j < 4; ++j) {
      S[j] = MFMA16(kf0[j], qf0, S[j]);
      S[j] = MFMA16(kf1[j], qf1, S[j]);
    }
#pragma unroll
    for (int j = 0; j < 4; ++j) {
      f32x4 cb = *(const f32x4*)&covb[j * 16 + quad * 4];
#pragma unroll
      for (int r = 0; r < 4; ++r)
        cs[j][r] += exp2f(S[j][r] * C1 + cb[r]) * lv;
    }
  }
#pragma unroll
  for (int j = 0; j < 4; ++j)
#pragma unroll
    for (int r = 0; r < 4; ++r) {
      float v = cs[j][r];
      v += __shfl_xor(v, 1);
      v += __shfl_xor(v, 2);
      v += __shfl_xor(v, 4);
      v += __shfl_xor(v, 8);
      if (c == 0) atomicAdd(&covsum[j * 16 + quad * 4 + r], v);
    }
  __syncthreads();
  if (tid < 64)
    atomicAdd(&covout[b * 1024 + k0 + tid], covsum[tid] * 0.0625f);
}

extern "C" void kernel_launch(void* const* d_in, const int* in_sizes, int n_in,
                              void* d_out, int out_size, void* d_ws,
                              size_t ws_size, hipStream_t stream) {
  const float* query = (const float*)d_in[0];
  const float* memory = (const float*)d_in[1];
  const float* coverage = (const float*)d_in[2];
  const float* Wq = (const float*)d_in[3];
  const float* bq = (const float*)d_in[4];
  const float* Wk = (const float*)d_in[5];
  const float* bk = (const float*)d_in[6];
  const float* Wv = (const float*)d_in[7];
  const float* bv = (const float*)d_in[8];
  const float* Wo = (const float*)d_in[9];
  const float* bo = (const float*)d_in[10];
  const float* Wcov = (const float*)d_in[11];

  char* w = (char*)d_ws;
  const size_t MB = 1024 * 1024;
  bf16_t* Xq = (bf16_t*)(w + 0);
  bf16_t* Xm = (bf16_t*)(w + 16 * MB);
  bf16_t* Wqb = (bf16_t*)(w + 32 * MB);
  bf16_t* Wkb = (bf16_t*)(w + 34 * MB);
  bf16_t* Wvb = (bf16_t*)(w + 36 * MB);
  bf16_t* Wob = (bf16_t*)(w + 38 * MB);
  bf16_t* Qp = (bf16_t*)(w + 40 * MB);
  bf16_t* Kp = (bf16_t*)(w + 56 * MB);
  bf16_t* Vt = (bf16_t*)(w + 72 * MB);
  bf16_t* Hb = (bf16_t*)(w + 0);        // reuses Xq (dead after Q projection)
  float* linvG = (float*)(w + 16 * MB); // reuses Xm (dead after V projection)

  float* out = (float*)d_out;
  float* covout = out + (size_t)8 * 1024 * 1024;

  convert_kernel<<<10244, 256, 0, stream>>>(query, memory, Wq, Wk, Wv, Wo,
                                            coverage, Xq, Xm, Wqb, Wkb, Wvb,
                                            Wob, covout);
  gemm_nt<0><<<dim3(64, 8), 256, 0, stream>>>(Xq, Wqb, bq, Qp);
  gemm_nt<0><<<dim3(64, 8), 256, 0, stream>>>(Xm, Wkb, bk, Kp);
  gemm_nt<2><<<dim3(64, 8), 256, 0, stream>>>(Xm, Wvb, bv, Vt);
  attn_fwd<<<dim3(16, 16, 8), 256, 0, stream>>>(Qp, Kp, Vt, coverage, Wcov,
                                                Hb, linvG);
  gemm_nt<1><<<dim3(64, 8), 256, 0, stream>>>(Hb, Wob, bo, out);
  cov_kernel<<<dim3(16, 16, 8), 256, 0, stream>>>(Qp, Kp, coverage, Wcov,
                                                  linvG, covout);
}